// Round 7
// baseline (115.730 us; speedup 1.0000x reference)
//
#include <hip/hip_runtime.h>
#include <hip/hip_bf16.h>
#include <math.h>

#define Bn 4
#define Cn 64
#define Pn 4096   // 64*64
#define QT 32     // q-tile per block
#define PBK 128   // p-block per flash iteration
#define NITER (Pn / PBK)
#define LOG2E 1.4426950408889634f

typedef __attribute__((ext_vector_type(8))) short short8;   // 8 bf16 = 4 VGPRs (MFMA A/B frag)
typedef __attribute__((ext_vector_type(4))) float float4v;  // MFMA C/D frag
typedef unsigned short bfu;

__device__ __forceinline__ bfu f2bf(float x) {
    unsigned u = __float_as_uint(x);
    u = (u + 0x7fffu + ((u >> 16) & 1u)) >> 16;   // RNE; inputs finite
    return (bfu)u;
}

// async global->LDS DMA, 16B per lane; LDS dest = base + lane*16 (wave-uniform base)
__device__ __forceinline__ void async_load16(const bfu* g, bfu* l) {
    __builtin_amdgcn_global_load_lds(
        (const __attribute__((address_space(1))) unsigned int*)(const void*)g,
        (__attribute__((address_space(3))) unsigned int*)(void*)l,
        16, 0, 0);
}

// ---------------------------------------------------------------------------
// Prep (unchanged from R6): 768 blocks, 16KB LDS.
//   blocks [0,512):   knorm -> bf16 Kpc [B][P][C] + Kcp [B][C][P]
//   blocks [512,768): 3x3 zero-padded box-sum * log2(e) -> S [B][C][P]
// ---------------------------------------------------------------------------
__global__ __launch_bounds__(256) void prep_kernel(const float* __restrict__ fg,
                                                   bfu* __restrict__ Kpc,
                                                   bfu* __restrict__ Kcp,
                                                   float* __restrict__ S) {
    __shared__ float shbuf[64 * 64];
    int t = threadIdx.x;
    if (blockIdx.x < 512) {
        float* tile  = shbuf;            // [64c][32p] stride 33
        float* rnorm = shbuf + 64 * 33;
        int b  = blockIdx.x >> 7;
        int p0 = (blockIdx.x & 127) << 5;
        const float* src = fg + (size_t)b * Cn * Pn + p0;
        #pragma unroll
        for (int i = 0; i < 8; ++i) {
            int idx = i * 256 + t;
            int c = idx >> 5, p = idx & 31;
            tile[c * 33 + p] = src[(size_t)c * Pn + p];
        }
        __syncthreads();
        if (t < 32) {
            float ss = 0.f;
            #pragma unroll
            for (int c = 0; c < 64; ++c) { float v = tile[c * 33 + t]; ss += v * v; }
            rnorm[t] = 1.0f / (sqrtf(ss) + 1e-8f);
        }
        __syncthreads();
        bfu* dpc = Kpc + ((size_t)b * Pn + p0) * Cn;
        #pragma unroll
        for (int i = 0; i < 8; ++i) {
            int idx = i * 256 + t;
            int p = idx >> 6, c = idx & 63;
            dpc[(size_t)p * Cn + c] = f2bf(tile[c * 33 + p] * rnorm[p]);
        }
        bfu* dcp = Kcp + (size_t)b * Cn * Pn + p0;
        #pragma unroll
        for (int i = 0; i < 8; ++i) {
            int idx = i * 256 + t;
            int c = idx >> 5, p = idx & 31;
            dcp[(size_t)c * Pn + p] = f2bf(tile[c * 33 + p] * rnorm[p]);
        }
    } else {
        float (*pl)[64] = (float(*)[64])shbuf;
        int bc = blockIdx.x - 512;
        const float* src = fg + (size_t)bc * Pn;
        float*       dst = S  + (size_t)bc * Pn;
        #pragma unroll
        for (int i = 0; i < 16; ++i) {
            int idx = i * 256 + t;
            pl[idx >> 6][idx & 63] = src[idx];
        }
        __syncthreads();
        #pragma unroll
        for (int i = 0; i < 16; ++i) {
            int idx = i * 256 + t;
            int h = idx >> 6, w = idx & 63;
            float s = 0.f;
            #pragma unroll
            for (int dh = -1; dh <= 1; ++dh) {
                int hh = h + dh;
                if (hh < 0 || hh >= 64) continue;
                #pragma unroll
                for (int dw = -1; dw <= 1; ++dw) {
                    int ww = w + dw;
                    if (ww < 0 || ww >= 64) continue;
                    s += pl[hh][ww];
                }
            }
            dst[idx] = s * LOG2E;
        }
    }
}

// ---------------------------------------------------------------------------
// Flash: out[:,q] = K^T exp2(K·S'_q) / l_q, wave-private p-ownership.
// Wave w owns p in [32w,32w+32) for BOTH score and accum (K=32 accum MFMAs);
// exp-scores move C-layout -> B-layout in-register via __shfl (no El LDS
// round-trip, no mid-iteration barrier). Per-wave partial outputs o[4][2]
// (full 64c x 32q over the wave's p-subset) are combined across waves once
// at the end through LDS. 1 barrier per K-iteration.
// ---------------------------------------------------------------------------
__global__ __launch_bounds__(256, 2) void flash_kernel(const bfu* __restrict__ Kpc,
                                                       const bfu* __restrict__ Kcp,
                                                       const float* __restrict__ S,
                                                       float* __restrict__ out) {
    // layout: Kpc buf0 [0,8192) buf1 [8192,16384) | Kcp buf0 [16384,24576)
    //         buf1 [24576,32768) | Sl [32768,34816)   (bfu units; 69.6 KB)
    __shared__ __align__(16) bfu smem[2 * PBK * 64 + 2 * Cn * PBK + QT * 64];
    __shared__ float wredl[4][QT];
    bfu* Sl = smem + 2 * PBK * 64 + 2 * Cn * PBK;

    int b  = blockIdx.x >> 7;
    int q0 = (blockIdx.x & 127) * QT;
    int t  = threadIdx.x;
    int w = t >> 6, l = t & 63, lq = l & 15, quad = l >> 4;

    const float* Sg  = S   + (size_t)b * Cn * Pn;
    const bfu*   gpc = Kpc + (size_t)b * Pn * Cn;
    const bfu*   gcp = Kcp + (size_t)b * Cn * Pn;

    // Sl[q][c] = bf16(Sg[c][q0+q])  (S pre-scaled by log2e), XOR-swizzled
    {
        int c = t >> 2, qq = (t & 3) * 8;
        const float* sp = &Sg[(size_t)c * Pn + q0 + qq];
        float4 v0 = *(const float4*)sp;
        float4 v1 = *(const float4*)(sp + 4);
        float vv[8] = {v0.x, v0.y, v0.z, v0.w, v1.x, v1.y, v1.z, v1.w};
        int ch = c >> 3, cl = c & 7;
        #pragma unroll
        for (int i = 0; i < 8; ++i) {
            int row = qq + i;
            Sl[row * 64 + ((ch ^ (row & 7)) << 3) + cl] = f2bf(vv[i]);
        }
    }

    // stage K(0) into buffer 0
    #pragma unroll
    for (int j = 0; j < 4; ++j) {
        int ci = (w * 4 + j) * 64 + l;
        int row = ci >> 3, chp = ci & 7;
        async_load16(gpc + (size_t)row * Cn + ((chp ^ (row & 7)) << 3),
                     smem + (w * 4 + j) * 512);
    }
    #pragma unroll
    for (int j = 0; j < 4; ++j) {
        int ci = (w * 4 + j) * 64 + l;
        int c = ci >> 4, chp = ci & 15;
        async_load16(gcp + (size_t)c * Pn + ((chp ^ (c & 15)) << 3),
                     smem + 2 * PBK * 64 + (w * 4 + j) * 512);
    }
    __syncthreads();   // Sl visible + K(0) DMA drained

    // hoist S B-frags: B[k=c][n=q], n=lq(+16nt), k=quad*8+j (+32ks)
    short8 bs[2][2];
    #pragma unroll
    for (int nt = 0; nt < 2; ++nt)
        #pragma unroll
        for (int ks = 0; ks < 2; ++ks) {
            int row = nt * 16 + lq;
            bs[nt][ks] = *(const short8*)&Sl[row * 64 + (((ks * 4 + quad) ^ (lq & 7)) << 3)];
        }

    float4v o[4][2];
    #pragma unroll
    for (int ct = 0; ct < 4; ++ct)
        #pragma unroll
        for (int nt = 0; nt < 2; ++nt) o[ct][nt] = (float4v){0.f, 0.f, 0.f, 0.f};
    float lacc[2] = {0.f, 0.f};

    // shfl source lanes for the C->B transpose (constant over loop)
    int s0 = ((quad & 1) * 2) * 16 + lq;   // qc = 2(quad&1)
    int s1 = s0 + 16;                      // qc = 2(quad&1)+1
    bool hi = quad >= 2;                   // mt = quad>>1

    for (int pb = 0; pb < NITER; ++pb) {
        bfu* KpcC = smem + (pb & 1) * (PBK * 64);
        bfu* KcpC = smem + 2 * PBK * 64 + (pb & 1) * (Cn * PBK);

        // ---- issue DMA for K(pb+1); lands before next iter's barrier exit ----
        if (pb + 1 < NITER) {
            bfu* KpcN = smem + ((pb + 1) & 1) * (PBK * 64);
            bfu* KcpN = smem + 2 * PBK * 64 + ((pb + 1) & 1) * (Cn * PBK);
            const bfu* gpc_n = gpc + (size_t)(pb + 1) * PBK * Cn;
            const bfu* gcp_n = gcp + (size_t)(pb + 1) * PBK;
            #pragma unroll
            for (int j = 0; j < 4; ++j) {
                int ci = (w * 4 + j) * 64 + l;
                int row = ci >> 3, chp = ci & 7;
                async_load16(gpc_n + (size_t)row * Cn + ((chp ^ (row & 7)) << 3),
                             KpcN + (w * 4 + j) * 512);
            }
            #pragma unroll
            for (int j = 0; j < 4; ++j) {
                int ci = (w * 4 + j) * 64 + l;
                int c = ci >> 4, chp = ci & 15;
                async_load16(gcp_n + (size_t)c * Pn + ((chp ^ (c & 15)) << 3),
                             KcpN + (w * 4 + j) * 512);
            }
        }

        // ---- score GEMM: wave w owns p rows [32w, 32w+32) ----
        short8 af[2][2];
        #pragma unroll
        for (int mt = 0; mt < 2; ++mt)
            #pragma unroll
            for (int ks = 0; ks < 2; ++ks) {
                int row = w * 32 + mt * 16 + lq;
                af[mt][ks] = *(const short8*)&KpcC[row * 64 + (((ks * 4 + quad) ^ (lq & 7)) << 3)];
            }
        float4v sc[2][2];
        #pragma unroll
        for (int mt = 0; mt < 2; ++mt)
            #pragma unroll
            for (int nt = 0; nt < 2; ++nt) {
                float4v acc = (float4v){0.f, 0.f, 0.f, 0.f};
                acc = __builtin_amdgcn_mfma_f32_16x16x32_bf16(af[mt][0], bs[nt][0], acc, 0, 0, 0);
                acc = __builtin_amdgcn_mfma_f32_16x16x32_bf16(af[mt][1], bs[nt][1], acc, 0, 0, 0);
                sc[mt][nt] = acc;
            }

        // ---- exp2 + per-lane denominator + bf16 pack ----
        // lane holds q = 16nt+lq, p_local32 = 16mt + 4quad + r
        unsigned pk[2][2][2];
        #pragma unroll
        for (int nt = 0; nt < 2; ++nt)
            #pragma unroll
            for (int mt = 0; mt < 2; ++mt) {
                float e0 = __builtin_amdgcn_exp2f(sc[mt][nt][0]);
                float e1 = __builtin_amdgcn_exp2f(sc[mt][nt][1]);
                float e2 = __builtin_amdgcn_exp2f(sc[mt][nt][2]);
                float e3 = __builtin_amdgcn_exp2f(sc[mt][nt][3]);
                lacc[nt] += (e0 + e1) + (e2 + e3);
                __hip_bfloat162 h01 = __float22bfloat162_rn(make_float2(e0, e1));
                __hip_bfloat162 h23 = __float22bfloat162_rn(make_float2(e2, e3));
                pk[mt][nt][0] = *(unsigned*)&h01;
                pk[mt][nt][1] = *(unsigned*)&h23;
            }

        // ---- in-register C-layout -> B-layout transpose (cross-quad shfl) ----
        // target (quad,lq) dword d holds E[k=quad*8+2d..2d+1][q=16nt+lq];
        // source lane = (2(quad&1)+(d>>1))*16+lq, source reg pk[quad>>1][nt][d&1]
        short8 eb[2];
        #pragma unroll
        for (int nt = 0; nt < 2; ++nt) {
            unsigned a, bq;
            uint4 bw;
            a  = (unsigned)__shfl((int)pk[0][nt][0], s0);
            bq = (unsigned)__shfl((int)pk[1][nt][0], s0);
            bw.x = hi ? bq : a;
            a  = (unsigned)__shfl((int)pk[0][nt][1], s0);
            bq = (unsigned)__shfl((int)pk[1][nt][1], s0);
            bw.y = hi ? bq : a;
            a  = (unsigned)__shfl((int)pk[0][nt][0], s1);
            bq = (unsigned)__shfl((int)pk[1][nt][0], s1);
            bw.z = hi ? bq : a;
            a  = (unsigned)__shfl((int)pk[0][nt][1], s1);
            bq = (unsigned)__shfl((int)pk[1][nt][1], s1);
            bw.w = hi ? bq : a;
            eb[nt] = *(short8*)&bw;
        }

        // ---- accum GEMM (wave-private K=32): o[ct][nt] += Kcp(c,:) · E ----
        #pragma unroll
        for (int ct = 0; ct < 4; ++ct) {
            int row = ct * 16 + lq;
            short8 ak = *(const short8*)&KcpC[row * PBK + (((4 * w + quad) ^ (row & 15)) << 3)];
            #pragma unroll
            for (int nt = 0; nt < 2; ++nt)
                o[ct][nt] = __builtin_amdgcn_mfma_f32_16x16x32_bf16(ak, eb[nt], o[ct][nt], 0, 0, 0);
        }
        __syncthreads();   // cur reads done (next DMA may overwrite) + K(pb+1) drained
    }

    // ---- denominator: reduce over quads, then over waves ----
    #pragma unroll
    for (int nt = 0; nt < 2; ++nt) {
        lacc[nt] += __shfl_xor(lacc[nt], 16);
        lacc[nt] += __shfl_xor(lacc[nt], 32);
    }
    if (quad == 0) { wredl[w][lq] = lacc[0]; wredl[w][16 + lq] = lacc[1]; }
    __syncthreads();
    float linv[2];
    #pragma unroll
    for (int nt = 0; nt < 2; ++nt) {
        int q = nt * 16 + lq;
        linv[nt] = 1.0f / ((wredl[0][q] + wredl[1][q]) + (wredl[2][q] + wredl[3][q]));
    }

    // ---- cross-wave combine of o partials via LDS (overlays K buffers) ----
    float* Ol = (float*)smem;   // [4w][64c][33] = 33792 B < 64 KB region
    #pragma unroll
    for (int ct = 0; ct < 4; ++ct)
        #pragma unroll
        for (int nt = 0; nt < 2; ++nt)
            #pragma unroll
            for (int r = 0; r < 4; ++r)
                Ol[(w * 64 + ct * 16 + quad * 4 + r) * 33 + nt * 16 + lq] = o[ct][nt][r] * linv[nt];
    __syncthreads();
    float* og = out + (size_t)b * Cn * Pn;
    #pragma unroll
    for (int i = 0; i < 8; ++i) {
        int idx = i * 256 + t;
        int c = idx >> 5, q = idx & 31;
        float v = (Ol[(c)*33 + q] + Ol[(64 + c) * 33 + q]) +
                  (Ol[(128 + c) * 33 + q] + Ol[(192 + c) * 33 + q]);
        og[(size_t)c * Pn + q0 + q] = v;
    }
}

// ---------------------------------------------------------------------------
extern "C" void kernel_launch(void* const* d_in, const int* in_sizes, int n_in,
                              void* d_out, int out_size, void* d_ws, size_t ws_size,
                              hipStream_t stream) {
    const float* fg = (const float*)d_in[0];
    float* out = (float*)d_out;
    bfu*   Kpc = (bfu*)d_ws;                               // 2 MB  bf16 [B][P][C]
    bfu*   Kcp = Kpc + (size_t)Bn * Pn * Cn;               // 2 MB  bf16 [B][C][P]
    float* S   = (float*)(Kcp + (size_t)Bn * Pn * Cn);     // 4 MB  fp32 [B][C][P] (pre-scaled by log2e)

    prep_kernel <<<768, 256, 0, stream>>>(fg, Kpc, Kcp, S);
    flash_kernel<<<Bn * 128, 256, 0, stream>>>(Kpc, Kcp, S, out);
}

// Round 8
// 102.939 us; speedup vs baseline: 1.1243x; 1.1243x over previous
//
#include <hip/hip_runtime.h>
#include <hip/hip_bf16.h>
#include <math.h>

#define Bn 4
#define Cn 64
#define Pn 4096   // 64*64
#define QT 32     // q-tile per block
#define PBK 128   // p-block per flash iteration
#define NITER (Pn / PBK)
#define LOG2E 1.4426950408889634f

typedef __attribute__((ext_vector_type(8))) short short8;   // 8 bf16 = 4 VGPRs (MFMA A/B frag)
typedef __attribute__((ext_vector_type(4))) float float4v;  // MFMA C/D frag
typedef unsigned short bfu;

__device__ __forceinline__ bfu f2bf(float x) {
    unsigned u = __float_as_uint(x);
    u = (u + 0x7fffu + ((u >> 16) & 1u)) >> 16;   // RNE; inputs finite
    return (bfu)u;
}

// async global->LDS DMA, 16B per lane; LDS dest = base + lane*16 (wave-uniform base)
__device__ __forceinline__ void async_load16(const bfu* g, bfu* l) {
    __builtin_amdgcn_global_load_lds(
        (const __attribute__((address_space(1))) unsigned int*)(const void*)g,
        (__attribute__((address_space(3))) unsigned int*)(void*)l,
        16, 0, 0);
}

// ---------------------------------------------------------------------------
// Prep (unchanged from R6): 768 blocks, 16KB LDS.
// ---------------------------------------------------------------------------
__global__ __launch_bounds__(256) void prep_kernel(const float* __restrict__ fg,
                                                   bfu* __restrict__ Kpc,
                                                   bfu* __restrict__ Kcp,
                                                   float* __restrict__ S) {
    __shared__ float shbuf[64 * 64];
    int t = threadIdx.x;
    if (blockIdx.x < 512) {
        float* tile  = shbuf;            // [64c][32p] stride 33
        float* rnorm = shbuf + 64 * 33;
        int b  = blockIdx.x >> 7;
        int p0 = (blockIdx.x & 127) << 5;
        const float* src = fg + (size_t)b * Cn * Pn + p0;
        #pragma unroll
        for (int i = 0; i < 8; ++i) {
            int idx = i * 256 + t;
            int c = idx >> 5, p = idx & 31;
            tile[c * 33 + p] = src[(size_t)c * Pn + p];
        }
        __syncthreads();
        if (t < 32) {
            float ss = 0.f;
            #pragma unroll
            for (int c = 0; c < 64; ++c) { float v = tile[c * 33 + t]; ss += v * v; }
            rnorm[t] = 1.0f / (sqrtf(ss) + 1e-8f);
        }
        __syncthreads();
        bfu* dpc = Kpc + ((size_t)b * Pn + p0) * Cn;
        #pragma unroll
        for (int i = 0; i < 8; ++i) {
            int idx = i * 256 + t;
            int p = idx >> 6, c = idx & 63;
            dpc[(size_t)p * Cn + c] = f2bf(tile[c * 33 + p] * rnorm[p]);
        }
        bfu* dcp = Kcp + (size_t)b * Cn * Pn + p0;
        #pragma unroll
        for (int i = 0; i < 8; ++i) {
            int idx = i * 256 + t;
            int c = idx >> 5, p = idx & 31;
            dcp[(size_t)c * Pn + p] = f2bf(tile[c * 33 + p] * rnorm[p]);
        }
    } else {
        float (*pl)[64] = (float(*)[64])shbuf;
        int bc = blockIdx.x - 512;
        const float* src = fg + (size_t)bc * Pn;
        float*       dst = S  + (size_t)bc * Pn;
        #pragma unroll
        for (int i = 0; i < 16; ++i) {
            int idx = i * 256 + t;
            pl[idx >> 6][idx & 63] = src[idx];
        }
        __syncthreads();
        #pragma unroll
        for (int i = 0; i < 16; ++i) {
            int idx = i * 256 + t;
            int h = idx >> 6, w = idx & 63;
            float s = 0.f;
            #pragma unroll
            for (int dh = -1; dh <= 1; ++dh) {
                int hh = h + dh;
                if (hh < 0 || hh >= 64) continue;
                #pragma unroll
                for (int dw = -1; dw <= 1; ++dw) {
                    int ww = w + dw;
                    if (ww < 0 || ww >= 64) continue;
                    s += pl[hh][ww];
                }
            }
            dst[idx] = s * LOG2E;
        }
    }
}

// ---------------------------------------------------------------------------
// Flash, R6 dataflow at 512 threads (8 waves): out[:,q] = K^T exp2(K·S'_q)/l_q
// grid = B*128 (QT=32); p in blocks of 128. 77KB LDS -> 2 blocks/CU
// -> 16 waves/CU (2x R6's occupancy, same total work).
//   score: wave w owns p-rows [16w,16w+16)
//   accum: wave w owns c-rows [16(w&3),+16) over p-half [64*(w>>2),+64);
//          halves combined in the epilogue via LDS overlay.
// ---------------------------------------------------------------------------
__global__ __launch_bounds__(512, 2) void flash_kernel(const bfu* __restrict__ Kpc,
                                                       const bfu* __restrict__ Kcp,
                                                       const float* __restrict__ S,
                                                       float* __restrict__ out) {
    // bfu units: Kpc dbuf [0,16384) | Kcp dbuf [16384,32768) | Sl [32768,34816)
    //            El [34816,38912)      = 77824 B
    __shared__ __align__(16) bfu smem[2 * PBK * 64 + 2 * Cn * PBK + QT * 64 + QT * PBK];
    __shared__ float wredl[8][QT];
    bfu* Sl = smem + 2 * PBK * 64 + 2 * Cn * PBK;
    bfu* El = Sl + QT * 64;

    int b  = blockIdx.x >> 7;
    int q0 = (blockIdx.x & 127) * QT;
    int t  = threadIdx.x;
    int w = t >> 6, l = t & 63, lq = l & 15, quad = l >> 4;

    const float* Sg  = S   + (size_t)b * Cn * Pn;
    const bfu*   gpc = Kpc + (size_t)b * Pn * Cn;
    const bfu*   gcp = Kcp + (size_t)b * Cn * Pn;

    // Sl[q][c] = bf16(Sg[c][q0+q])  (S pre-scaled by log2e), XOR-swizzled
    {
        int c = t >> 3, qq = (t & 7) * 4;
        const float* sp = &Sg[(size_t)c * Pn + q0 + qq];
        float4 v0 = *(const float4*)sp;
        float vv[4] = {v0.x, v0.y, v0.z, v0.w};
        int ch = c >> 3, cl = c & 7;
        #pragma unroll
        for (int i = 0; i < 4; ++i) {
            int row = qq + i;
            Sl[row * 64 + ((ch ^ (row & 7)) << 3) + cl] = f2bf(vv[i]);
        }
    }

    // stage K(0) into buffer 0: 1024 chunks each, group g = j*8+w covers 64 chunks
    #pragma unroll
    for (int j = 0; j < 2; ++j) {
        int g = j * 8 + w;
        int ci = g * 64 + l;
        int row = ci >> 3, chp = ci & 7;
        async_load16(gpc + (size_t)row * Cn + ((chp ^ (row & 7)) << 3), smem + g * 512);
    }
    #pragma unroll
    for (int j = 0; j < 2; ++j) {
        int g = j * 8 + w;
        int ci = g * 64 + l;
        int c = ci >> 4, chp = ci & 15;
        async_load16(gcp + (size_t)c * Pn + ((chp ^ (c & 15)) << 3),
                     smem + 2 * PBK * 64 + g * 512);
    }
    __syncthreads();   // Sl visible + K(0) DMA drained

    // hoist S B-frags: B[k=c][n=q], n=lq(+16nt), k=quad*8+j (+32ks)
    short8 bs[2][2];
    #pragma unroll
    for (int nt = 0; nt < 2; ++nt)
        #pragma unroll
        for (int ks = 0; ks < 2; ++ks) {
            int row = nt * 16 + lq;
            bs[nt][ks] = *(const short8*)&Sl[row * 64 + (((ks * 4 + quad) ^ (lq & 7)) << 3)];
        }

    float4v o[2];
    o[0] = (float4v){0.f, 0.f, 0.f, 0.f};
    o[1] = (float4v){0.f, 0.f, 0.f, 0.f};
    float lacc[2] = {0.f, 0.f};

    int h  = w >> 2;          // accum p-half
    int ca = (w & 3) * 16;    // accum c-row base

    for (int pb = 0; pb < NITER; ++pb) {
        bfu* KpcC = smem + (pb & 1) * (PBK * 64);
        bfu* KcpC = smem + 2 * PBK * 64 + (pb & 1) * (Cn * PBK);

        // ---- issue DMA for K(pb+1); drained by the end-of-iter barrier ----
        if (pb + 1 < NITER) {
            bfu* KpcN = smem + ((pb + 1) & 1) * (PBK * 64);
            bfu* KcpN = smem + 2 * PBK * 64 + ((pb + 1) & 1) * (Cn * PBK);
            const bfu* gpc_n = gpc + (size_t)(pb + 1) * PBK * Cn;
            const bfu* gcp_n = gcp + (size_t)(pb + 1) * PBK;
            #pragma unroll
            for (int j = 0; j < 2; ++j) {
                int g = j * 8 + w;
                int ci = g * 64 + l;
                int row = ci >> 3, chp = ci & 7;
                async_load16(gpc_n + (size_t)row * Cn + ((chp ^ (row & 7)) << 3),
                             KpcN + g * 512);
            }
            #pragma unroll
            for (int j = 0; j < 2; ++j) {
                int g = j * 8 + w;
                int ci = g * 64 + l;
                int c = ci >> 4, chp = ci & 15;
                async_load16(gcp_n + (size_t)c * Pn + ((chp ^ (c & 15)) << 3),
                             KcpN + g * 512);
            }
        }

        // ---- score GEMM: wave w owns p rows [16w, 16w+16) ----
        short8 af[2];
        #pragma unroll
        for (int ks = 0; ks < 2; ++ks) {
            int row = w * 16 + lq;
            af[ks] = *(const short8*)&KpcC[row * 64 + (((ks * 4 + quad) ^ (lq & 7)) << 3)];
        }
        float4v sc[2];
        #pragma unroll
        for (int nt = 0; nt < 2; ++nt) {
            float4v acc = (float4v){0.f, 0.f, 0.f, 0.f};
            acc = __builtin_amdgcn_mfma_f32_16x16x32_bf16(af[0], bs[nt][0], acc, 0, 0, 0);
            acc = __builtin_amdgcn_mfma_f32_16x16x32_bf16(af[1], bs[nt][1], acc, 0, 0, 0);
            sc[nt] = acc;
        }

        // ---- exp2 + per-lane denominator + El pack (bf16) ----
        // lane holds q = 16nt+lq, p = 16w + 4quad + r
        #pragma unroll
        for (int nt = 0; nt < 2; ++nt) {
            int row = nt * 16 + lq;
            float e0 = __builtin_amdgcn_exp2f(sc[nt][0]);
            float e1 = __builtin_amdgcn_exp2f(sc[nt][1]);
            float e2 = __builtin_amdgcn_exp2f(sc[nt][2]);
            float e3 = __builtin_amdgcn_exp2f(sc[nt][3]);
            lacc[nt] += (e0 + e1) + (e2 + e3);
            __hip_bfloat162 h01 = __float22bfloat162_rn(make_float2(e0, e1));
            __hip_bfloat162 h23 = __float22bfloat162_rn(make_float2(e2, e3));
            uint2 pk = make_uint2(*(unsigned*)&h01, *(unsigned*)&h23);
            int col = w * 16 + quad * 4;
            int ch = (col >> 3) ^ (row & 15), cl = col & 7;
            *(uint2*)&El[row * PBK + ch * 8 + cl] = pk;
        }
        __syncthreads();   // El(pb) visible

        // ---- accum GEMM: wave w owns c [ca,ca+16) over p-half [64h,64h+64) ----
        #pragma unroll
        for (int ks = 0; ks < 2; ++ks) {
            int rowA = ca + lq;
            short8 ak = *(const short8*)&KcpC[rowA * PBK + (((8 * h + ks * 4 + quad) ^ (rowA & 15)) << 3)];
            #pragma unroll
            for (int nt = 0; nt < 2; ++nt) {
                int rowB = nt * 16 + lq;
                short8 bk = *(const short8*)&El[rowB * PBK + (((8 * h + ks * 4 + quad) ^ (rowB & 15)) << 3)];
                o[nt] = __builtin_amdgcn_mfma_f32_16x16x32_bf16(ak, bk, o[nt], 0, 0, 0);
            }
        }
        __syncthreads();   // El free; K(pb+1) DMA drained
    }

    // ---- denominator: quad-reduce then cross-wave sum ----
    #pragma unroll
    for (int nt = 0; nt < 2; ++nt) {
        lacc[nt] += __shfl_xor(lacc[nt], 16);
        lacc[nt] += __shfl_xor(lacc[nt], 32);
    }
    if (quad == 0) { wredl[w][lq] = lacc[0]; wredl[w][16 + lq] = lacc[1]; }

    // ---- combine the two p-halves via LDS overlay (K-buffer region) ----
    float* Ol = (float*)smem;   // [2h][64c][33] = 16896 B < 64 KB region
    __syncthreads();            // wredl visible; all K reads done
    #pragma unroll
    for (int nt = 0; nt < 2; ++nt)
        #pragma unroll
        for (int r = 0; r < 4; ++r)
            Ol[(h * 64 + ca + quad * 4 + r) * 33 + nt * 16 + lq] = o[nt][r];
    __syncthreads();
    float* og = out + (size_t)b * Cn * Pn;
    #pragma unroll
    for (int i = 0; i < 4; ++i) {
        int idx = i * 512 + t;
        int c = idx >> 5, q = idx & 31;
        float lsum = ((wredl[0][q] + wredl[1][q]) + (wredl[2][q] + wredl[3][q])) +
                     ((wredl[4][q] + wredl[5][q]) + (wredl[6][q] + wredl[7][q]));
        float v = (Ol[c * 33 + q] + Ol[(64 + c) * 33 + q]) / lsum;
        og[(size_t)c * Pn + q0 + q] = v;
    }
}

// ---------------------------------------------------------------------------
extern "C" void kernel_launch(void* const* d_in, const int* in_sizes, int n_in,
                              void* d_out, int out_size, void* d_ws, size_t ws_size,
                              hipStream_t stream) {
    const float* fg = (const float*)d_in[0];
    float* out = (float*)d_out;
    bfu*   Kpc = (bfu*)d_ws;                               // 2 MB  bf16 [B][P][C]
    bfu*   Kcp = Kpc + (size_t)Bn * Pn * Cn;               // 2 MB  bf16 [B][C][P]
    float* S   = (float*)(Kcp + (size_t)Bn * Pn * Cn);     // 4 MB  fp32 [B][C][P] (pre-scaled by log2e)

    prep_kernel <<<768, 256, 0, stream>>>(fg, Kpc, Kcp, S);
    flash_kernel<<<Bn * 128, 512, 0, stream>>>(Kpc, Kcp, S, out);
}